// Round 8
// baseline (270.852 us; speedup 1.0000x reference)
//
#include <hip/hip_runtime.h>

// Capsule dynamic routing — barrier-free: all-10-o per thread, eq on low lanes.
// u_i:(B,N,DI) f32, w:(1,N,NO,DI,DE) f32, bias:(N,NO,1) f32, r=3.
// Identity: logits_r = u_ji . vsum (vsum = running sum of v; u_ji includes
// bias so the bias term folds in automatically).
// Lane map: eq = lane&3 (e-quad), bb = lane>>2 (16 b per wave). Thread owns
// (b, all 10 o, 4 e). Logit dot reduced over eq via shfl_xor(1,2) -> softmax
// fully in-register; NO barriers, NO LDS in the routing hot loop.
// Per-wave traffic/n: u = 16x32B segments; each w float4 load = one 64B line.
// VGPR budget ~150 (uji/acc/vv = 120) under cap 170 at launch_bounds(256,3);
// spill signature (R6): FETCH/WRITE balloon -> none expected.

#define B    256
#define N    1152
#define NO   10
#define DI   8
#define DE   16
#define NTILE   8
#define NTILES  144    // N / NTILE
#define THREADS 256    // 4 waves; each wave covers 16 b -> block covers 64 b
#define BGS     4      // B / 64

// ws layout (floats) — 23.76 MB (unchanged)
#define SP_OFF 0
#define SP_SZ  (NTILES * B * NO * DE)   // 5,898,240
#define VS_OFF (SP_OFF + SP_SZ)
#define VS_SZ  (B * NO * DE)            // 40,960

// ---------------------------------------------------------------------------
// Routing pass. Grid: (144 n-tiles, 4 b-groups) x 256 threads.
// ---------------------------------------------------------------------------
__global__ __launch_bounds__(THREADS, 3)
void routing_kernel(const float* __restrict__ u,
                    const float* __restrict__ w,
                    const float* __restrict__ bias,
                    const float* __restrict__ vsum,
                    float* __restrict__ s_part,
                    const int has_v) {
    const int tid  = threadIdx.x;
    const int lane = tid & 63;
    const int eq   = lane & 3;        // e-quad: e = eq*4..eq*4+3
    const int bb   = lane >> 2;       // 0..15
    const int wv   = tid >> 6;        // wave id -> b sub-group
    const int b    = blockIdx.y * 64 + wv * 16 + bb;
    const int n0   = blockIdx.x * NTILE;

    // vsum fragments (loop-invariant): vv[o] = vsum[b][o][eq*4..+3]
    float4 vv[NO];
#pragma unroll
    for (int o = 0; o < NO; ++o) vv[o] = make_float4(0.f, 0.f, 0.f, 0.f);
    if (has_v) {
#pragma unroll
        for (int o = 0; o < NO; ++o)
            vv[o] = *(const float4*)(vsum + ((size_t)b * NO + o) * DE + eq * 4);
    }

    float4 acc[NO];
#pragma unroll
    for (int o = 0; o < NO; ++o) acc[o] = make_float4(0.f, 0.f, 0.f, 0.f);

    for (int i = 0; i < NTILE; ++i) {
        const int n = n0 + i;

        // u row for this b (4 eq-lanes share addr -> 16 unique 32B segs/wave)
        const float* up = u + ((size_t)b * N + n) * DI;
        const float4 u0 = *(const float4*)up;
        const float4 u1 = *(const float4*)(up + 4);
        const float ur[DI] = {u0.x, u0.y, u0.z, u0.w, u1.x, u1.y, u1.z, u1.w};

        // u_ji for all 10 o at this thread's e-quad.
        // w addr varies only with eq across the wave -> one 64B line per load.
        const float* wp = w + (size_t)n * (NO * DI * DE) + eq * 4;
        float4 uji[NO];
#pragma unroll
        for (int o = 0; o < NO; ++o) {
            const float bv = bias[n * NO + o];
            float4 a = make_float4(bv, bv, bv, bv);
            const float* wo = wp + o * (DI * DE);
#pragma unroll
            for (int d = 0; d < DI; ++d) {
                const float4 w4 = *(const float4*)(wo + d * DE);
                a.x += ur[d] * w4.x; a.y += ur[d] * w4.y;
                a.z += ur[d] * w4.z; a.w += ur[d] * w4.w;
            }
            uji[o] = a;
        }

        float c[NO];
        if (has_v) {
            // logits: partial dot over this eq, reduced across the eq quad
            float l[NO];
#pragma unroll
            for (int o = 0; o < NO; ++o) {
                float dt = uji[o].x * vv[o].x + uji[o].y * vv[o].y
                         + uji[o].z * vv[o].z + uji[o].w * vv[o].w;
                dt += __shfl_xor(dt, 1);
                dt += __shfl_xor(dt, 2);     // full 16-e dot, all eq lanes
                l[o] = dt;
            }
            // softmax over o — fully in-register
            float m = l[0];
#pragma unroll
            for (int o = 1; o < NO; ++o) m = fmaxf(m, l[o]);
            float sum = 0.f;
#pragma unroll
            for (int o = 0; o < NO; ++o) { c[o] = __expf(l[o] - m); sum += c[o]; }
            const float inv = 1.f / sum;
#pragma unroll
            for (int o = 0; o < NO; ++o) c[o] *= inv;
        } else {
#pragma unroll
            for (int o = 0; o < NO; ++o) c[o] = 0.1f;   // softmax of zeros
        }

#pragma unroll
        for (int o = 0; o < NO; ++o) {
            acc[o].x += c[o] * uji[o].x; acc[o].y += c[o] * uji[o].y;
            acc[o].z += c[o] * uji[o].z; acc[o].w += c[o] * uji[o].w;
        }
    }

    // s_part[tile][b][o][e]
    float* sp = s_part + (((size_t)blockIdx.x * B + b) * NO) * DE + eq * 4;
#pragma unroll
    for (int o = 0; o < NO; ++o)
        *(float4*)(sp + o * DE) = acc[o];
}

// ---------------------------------------------------------------------------
// Squash: s = sum_tiles s_part; v = ||s||/(1+||s||^2)*s; out = v; vsum += v.
// 4 threads per element (36 tiles each). t0: q = t0&3, g = t0>>2 = (b*NO+o)*16+e.
// Wave = 4 q x 16 e of one (b,o): combine q via xor(1,2), norm via xor(4..32).
// ---------------------------------------------------------------------------
__global__ __launch_bounds__(256)
void squash_kernel(const float* __restrict__ s_part,
                   float* __restrict__ vsum,
                   float* __restrict__ out,
                   const int accum) {
    const int t0 = blockIdx.x * 256 + threadIdx.x;   // < 4*40960
    const int q  = t0 & 3;
    const int g  = t0 >> 2;

    float s = 0.f;
    const float* sp = s_part + (size_t)(q * 36) * (B * NO * DE) + g;
#pragma unroll 9
    for (int i = 0; i < 36; ++i)
        s += sp[(size_t)i * (B * NO * DE)];
    s += __shfl_xor(s, 1);
    s += __shfl_xor(s, 2);        // full tile sum, all q lanes

    float nsq = s * s;
#pragma unroll
    for (int msk = 4; msk <= 32; msk <<= 1) nsq += __shfl_xor(nsq, msk);
    const float nrm   = sqrtf(nsq);
    const float scale = nrm / (1.f + nsq);
    const float val   = s * scale;

    if (q == 0) {
        out[g]  = val;                               // (B,NO,DE)
        vsum[g] = accum ? (vsum[g] + val) : val;
    }
}

extern "C" void kernel_launch(void* const* d_in, const int* in_sizes, int n_in,
                              void* d_out, int out_size, void* d_ws, size_t ws_size,
                              hipStream_t stream) {
    const float* u    = (const float*)d_in[0];
    const float* w    = (const float*)d_in[1];   // (N,NO,DI,DE)
    const float* bias = (const float*)d_in[2];   // (N,NO)
    // d_in[3] = r, static 3

    float* wsf    = (float*)d_ws;
    float* s_part = wsf + SP_OFF;
    float* vsum   = wsf + VS_OFF;
    float* out    = (float*)d_out;

    for (int it = 0; it < 3; ++it) {
        routing_kernel<<<dim3(NTILES, BGS), THREADS, 0, stream>>>(
            u, w, bias, vsum, s_part, it > 0);
        squash_kernel<<<(4 * B * NO * DE) / 256, 256, 0, stream>>>(
            s_part, vsum, out, it > 0);
    }
}